// Round 1
// baseline (102.852 us; speedup 1.0000x reference)
//
#include <hip/hip_runtime.h>

#define BB 4096
#define II 512
#define HH 1024
#define RR 128

typedef __bf16 bf16x8 __attribute__((ext_vector_type(8)));
typedef float  f32x4  __attribute__((ext_vector_type(4)));
typedef unsigned short u16x8 __attribute__((ext_vector_type(8)));
typedef unsigned short u16x4 __attribute__((ext_vector_type(4)));

__device__ __forceinline__ unsigned short f2bf(float f) {
  unsigned int u = __float_as_uint(f);
  u += 0x7fffu + ((u >> 16) & 1u);   // round-to-nearest-even
  return (unsigned short)(u >> 16);
}
__device__ __forceinline__ float sigm(float v) { return 1.f / (1.f + __expf(-v)); }
__device__ __forceinline__ float tanh_f(float v) { return 1.f - 2.f / (1.f + __expf(2.f * v)); }

// ---------------- workspace layout (bytes) ----------------
// T   : 0        .. 2097152   bf16 [4096][256]   (stage1 out = [x@Ux , h@Uh])
// VC  : 2097152  .. 4194304   bf16 [4096][256]   gate-interleaved V rows:
//                              row (jb*128 + g*32 + jj) = [V_x[g*1024+jb*32+jj][:] , V_h[...][:]]
// UTX : 4194304  .. 4325376   bf16 [128][512]    U_x^T
// UTH : 4325376  .. 4587520   bf16 [128][1024]   U_h^T
// CX  : 4587520  .. 4595712   f32  [4][512]      corr_x
// CH  : 4595712  .. 4612096   f32  [4][1024]     corr_h
// BC  : 4612096  .. 4628480   f32  [4096]        b_x + b_h

__global__ __launch_bounds__(256) void prep_kernel(
    const float* __restrict__ Ux, const float* __restrict__ Uh,
    const float* __restrict__ Vx, const float* __restrict__ Vh,
    const float* __restrict__ bx, const float* __restrict__ bh,
    unsigned short* __restrict__ VC, unsigned short* __restrict__ UTX,
    unsigned short* __restrict__ UTH, float* __restrict__ CX,
    float* __restrict__ CH, float* __restrict__ BC)
{
  int tid = blockIdx.x * 256 + threadIdx.x;
  if (tid < 131072) {                       // VC: gate-interleave + bf16, 8 elems/thread
    int row = tid >> 5, kc = tid & 31, k = kc * 8;
    int jb = row >> 7, nt = row & 127, g = nt >> 5, j = jb * 32 + (nt & 31);
    int vrow = g * HH + j;
    const float* src = (k < 128) ? (Vx + vrow * RR + k) : (Vh + vrow * RR + (k - 128));
    f32x4 a = *(const f32x4*)src;
    f32x4 b = *(const f32x4*)(src + 4);
    u16x8 o;
    o[0]=f2bf(a[0]); o[1]=f2bf(a[1]); o[2]=f2bf(a[2]); o[3]=f2bf(a[3]);
    o[4]=f2bf(b[0]); o[5]=f2bf(b[1]); o[6]=f2bf(b[2]); o[7]=f2bf(b[3]);
    *(u16x8*)(VC + row * 256 + k) = o;
  } else if (tid < 139264) {                // UTX: transpose U_x -> [n][k] bf16
    int idx = tid - 131072;
    int n = idx & 127, k = (idx >> 7) * 8;  // k < 512
    u16x8 o;
    #pragma unroll
    for (int e = 0; e < 8; ++e) o[e] = f2bf(Ux[(k + e) * RR + n]);
    *(u16x8*)(UTX + n * II + k) = o;
  } else if (tid < 155648) {                // UTH: transpose U_h -> [n][k] bf16
    int idx = tid - 139264;
    int n = idx & 127, k = (idx >> 7) * 8;  // k < 1024
    u16x8 o;
    #pragma unroll
    for (int e = 0; e < 8; ++e) o[e] = f2bf(Uh[(k + e) * RR + n]);
    *(u16x8*)(UTH + n * HH + k) = o;
  } else if (tid < 157696) {                // corr_x[g][i]
    int idx = tid - 155648;
    int g = idx >> 9, i = idx & 511;
    const float* u = Ux + i * RR;
    const float* v = Vx + (g * HH + i) * RR;
    float s = 0.f;
    #pragma unroll 8
    for (int r4 = 0; r4 < 32; ++r4) {
      f32x4 uu = *(const f32x4*)(u + r4 * 4);
      f32x4 vv = *(const f32x4*)(v + r4 * 4);
      s += uu[0]*vv[0] + uu[1]*vv[1] + uu[2]*vv[2] + uu[3]*vv[3];
    }
    CX[g * II + i] = s;
  } else if (tid < 161792) {                // corr_h[g][j]
    int idx = tid - 157696;
    int g = idx >> 10, j = idx & 1023;
    const float* u = Uh + j * RR;
    const float* v = Vh + (g * HH + j) * RR;
    float s = 0.f;
    #pragma unroll 8
    for (int r4 = 0; r4 < 32; ++r4) {
      f32x4 uu = *(const f32x4*)(u + r4 * 4);
      f32x4 vv = *(const f32x4*)(v + r4 * 4);
      s += uu[0]*vv[0] + uu[1]*vv[1] + uu[2]*vv[2] + uu[3]*vv[3];
    }
    CH[g * HH + j] = s;
  } else if (tid < 165888) {                // combined bias
    int n = tid - 161792;
    BC[n] = bx[n] + bh[n];
  }
}

// stage1: T[:, :128] = x @ U_x ; T[:, 128:] = h @ U_h   (bf16 out)
// 128 blocks: p = bid>>6 (0:x, 1:h), 64-row M tile, 4 waves x 16 rows.
__global__ __launch_bounds__(256) void stage1_kernel(
    const float* __restrict__ x, const float* __restrict__ h,
    const unsigned short* __restrict__ UTX, const unsigned short* __restrict__ UTH,
    unsigned short* __restrict__ T)
{
  __shared__ alignas(16) unsigned short As[64 * 136];   // +8 pad: conflict-free frag reads
  __shared__ alignas(16) unsigned short Bs[128 * 136];
  int t = threadIdx.x, l = t & 63, w = t >> 6;
  int p = blockIdx.x >> 6;
  int mb = blockIdx.x & 63;
  int b0 = mb * 64;
  const float* src = p ? h : x;
  const unsigned short* Ut = p ? UTH : UTX;
  int K = p ? HH : II;
  int nkt = K >> 7;

  f32x4 zero = {0.f, 0.f, 0.f, 0.f};
  f32x4 acc[8];
  #pragma unroll
  for (int fi = 0; fi < 8; ++fi) acc[fi] = zero;

  for (int kt = 0; kt < nkt; ++kt) {
    #pragma unroll
    for (int i = 0; i < 8; ++i) {           // A: 64x128 f32 -> bf16 LDS
      int f = i * 256 + t;
      int r = f >> 5, kc = (f & 31) * 4;
      f32x4 v = *(const f32x4*)(src + (b0 + r) * K + kt * 128 + kc);
      u16x4 o;
      o[0]=f2bf(v[0]); o[1]=f2bf(v[1]); o[2]=f2bf(v[2]); o[3]=f2bf(v[3]);
      *(u16x4*)(As + r * 136 + kc) = o;
    }
    #pragma unroll
    for (int i = 0; i < 8; ++i) {           // B: U^T tile 128x128 bf16
      int f = i * 256 + t;
      int n = f >> 4, kc = (f & 15) * 8;
      *(u16x8*)(Bs + n * 136 + kc) = *(const u16x8*)(Ut + n * K + kt * 128 + kc);
    }
    __syncthreads();
    int koff = (l >> 4) * 8;
    int arow = (w * 16 + (l & 15)) * 136 + koff;
    #pragma unroll
    for (int ks = 0; ks < 4; ++ks) {
      bf16x8 a = *(const bf16x8*)(As + arow + ks * 32);
      #pragma unroll
      for (int fi = 0; fi < 8; ++fi) {
        bf16x8 b = *(const bf16x8*)(Bs + (fi * 16 + (l & 15)) * 136 + ks * 32 + koff);
        acc[fi] = __builtin_amdgcn_mfma_f32_16x16x32_bf16(a, b, acc[fi], 0, 0, 0);
      }
    }
    __syncthreads();
  }
  int rbase = b0 + w * 16 + (l >> 4) * 4;
  int cbase = p * 128 + (l & 15);
  #pragma unroll
  for (int fi = 0; fi < 8; ++fi)
    #pragma unroll
    for (int reg = 0; reg < 4; ++reg)
      T[(rbase + reg) * 256 + cbase + fi * 16] = f2bf(acc[fi][reg]);
}

// stage2: G = T @ VC^T per (128-row, 32-j) tile; cols = 4 gates x 32 j. Fused epilogue.
// 1024 blocks x 512 threads, 8 waves x 16 rows. K=256 fully LDS-resident.
__global__ __launch_bounds__(512) void stage2_kernel(
    const unsigned short* __restrict__ T, const unsigned short* __restrict__ VC,
    const float* __restrict__ CX, const float* __restrict__ CH, const float* __restrict__ BC,
    const float* __restrict__ x, const float* __restrict__ h, const float* __restrict__ c,
    const float* __restrict__ dx, const float* __restrict__ dh,
    float* __restrict__ out)
{
  __shared__ alignas(16) unsigned short Ts[128 * 264];  // +8 pad
  __shared__ alignas(16) unsigned short Vs[128 * 264];
  int t = threadIdx.x, l = t & 63, w = t >> 6;
  int jb = blockIdx.x >> 5, mb = blockIdx.x & 31;
  int b0 = mb * 128, j0 = jb * 32;

  #pragma unroll
  for (int i = 0; i < 8; ++i) {
    int f = i * 512 + t;
    int r = f >> 5, kc = (f & 31) * 8;
    *(u16x8*)(Ts + r * 264 + kc) = *(const u16x8*)(T + (b0 + r) * 256 + kc);
    *(u16x8*)(Vs + r * 264 + kc) = *(const u16x8*)(VC + (jb * 128 + r) * 256 + kc);
  }
  __syncthreads();

  f32x4 zero = {0.f, 0.f, 0.f, 0.f};
  f32x4 acc[8];
  #pragma unroll
  for (int fi = 0; fi < 8; ++fi) acc[fi] = zero;

  int koff = (l >> 4) * 8;
  int arow = (w * 16 + (l & 15)) * 264 + koff;
  #pragma unroll
  for (int ks = 0; ks < 8; ++ks) {
    bf16x8 a = *(const bf16x8*)(Ts + arow + ks * 32);
    #pragma unroll
    for (int fi = 0; fi < 8; ++fi) {
      bf16x8 b = *(const bf16x8*)(Vs + (fi * 16 + (l & 15)) * 264 + ks * 32 + koff);
      acc[fi] = __builtin_amdgcn_mfma_f32_16x16x32_bf16(a, b, acc[fi], 0, 0, 0);
    }
  }

  // epilogue: fragment (fi = g*2 + hl), col nt = fi*16 + (l&15) = g*32 + hl*16 + (l&15)
  #pragma unroll
  for (int reg = 0; reg < 4; ++reg) {
    int b = b0 + w * 16 + (l >> 4) * 4 + reg;
    #pragma unroll
    for (int hl = 0; hl < 2; ++hl) {
      int j = j0 + hl * 16 + (l & 15);
      float hv = h[b * HH + j];
      float cv = c[b * HH + j];
      float addv = dh[j] * hv;
      float pre[4];
      #pragma unroll
      for (int g = 0; g < 4; ++g) pre[g] = acc[g * 2 + hl][reg];
      if (j0 < II) {
        float xv = x[b * II + j];
        addv += dx[j] * xv;
        #pragma unroll
        for (int g = 0; g < 4; ++g) pre[g] -= xv * CX[g * II + j];
      }
      #pragma unroll
      for (int g = 0; g < 4; ++g) pre[g] += BC[g * HH + j] + addv - hv * CH[g * HH + j];
      float ig = sigm(pre[0]);
      float fg = sigm(pre[1]);
      float og = sigm(pre[2]);
      float ng = tanh_f(pre[3]);
      float cn = fg * cv + ig * ng;
      float hn = og * tanh_f(cn);
      out[b * HH + j] = hn;
      out[BB * HH + b * HH + j] = cn;
    }
  }
}

extern "C" void kernel_launch(void* const* d_in, const int* in_sizes, int n_in,
                              void* d_out, int out_size, void* d_ws, size_t ws_size,
                              hipStream_t stream) {
  const float* x  = (const float*)d_in[0];
  const float* h  = (const float*)d_in[1];
  const float* c  = (const float*)d_in[2];
  const float* Ux = (const float*)d_in[3];
  const float* Uh = (const float*)d_in[4];
  const float* Vx = (const float*)d_in[5];
  const float* Vh = (const float*)d_in[6];
  const float* bx = (const float*)d_in[7];
  const float* bh = (const float*)d_in[8];
  const float* dx = (const float*)d_in[9];
  const float* dh = (const float*)d_in[10];
  char* ws = (char*)d_ws;
  unsigned short* T   = (unsigned short*)(ws + 0);
  unsigned short* VC  = (unsigned short*)(ws + 2097152);
  unsigned short* UTX = (unsigned short*)(ws + 4194304);
  unsigned short* UTH = (unsigned short*)(ws + 4325376);
  float* CX = (float*)(ws + 4587520);
  float* CH = (float*)(ws + 4595712);
  float* BC = (float*)(ws + 4612096);
  float* out = (float*)d_out;

  prep_kernel<<<648, 256, 0, stream>>>(Ux, Uh, Vx, Vh, bx, bh, VC, UTX, UTH, CX, CH, BC);
  stage1_kernel<<<128, 256, 0, stream>>>(x, h, UTX, UTH, T);
  stage2_kernel<<<1024, 512, 0, stream>>>(T, VC, CX, CH, BC, x, h, c, dx, dh, out);
}

// Round 2
// 59.833 us; speedup vs baseline: 1.7190x; 1.7190x over previous
//
#include <hip/hip_runtime.h>

#define BB 4096
#define II 512
#define HH 1024
#define RR 128

typedef __bf16 bf16x8 __attribute__((ext_vector_type(8)));
typedef float  f32x4  __attribute__((ext_vector_type(4)));
typedef unsigned short u16x8 __attribute__((ext_vector_type(8)));
typedef unsigned short u16x4 __attribute__((ext_vector_type(4)));

__device__ __forceinline__ unsigned short f2bf(float f) {
  unsigned int u = __float_as_uint(f);
  u += 0x7fffu + ((u >> 16) & 1u);   // round-to-nearest-even
  return (unsigned short)(u >> 16);
}
__device__ __forceinline__ float sigm(float v) { return 1.f / (1.f + __expf(-v)); }
__device__ __forceinline__ float tanh_f(float v) { return 1.f - 2.f / (1.f + __expf(2.f * v)); }

// ---------------- workspace layout (bytes) ----------------
// T   : 0        .. 2097152   bf16 [4096][256]   (stage1 out = [x@Ux , h@Uh])
// VC  : 2097152  .. 4194304   bf16 [4096][256]   gate-interleaved V rows
// UTX : 4194304  .. 4325376   bf16 [128][512]    U_x^T
// UTH : 4325376  .. 4587520   bf16 [128][1024]   U_h^T
// CX  : 4587520  .. 4595712   f32  [4][512]      corr_x
// CH  : 4595712  .. 4612096   f32  [4][1024]     corr_h
// BC  : 4612096  .. 4628480   f32  [4096]        b_x + b_h

__global__ __launch_bounds__(256) void prep_kernel(
    const float* __restrict__ Ux, const float* __restrict__ Uh,
    const float* __restrict__ Vx, const float* __restrict__ Vh,
    const float* __restrict__ bx, const float* __restrict__ bh,
    unsigned short* __restrict__ VC, unsigned short* __restrict__ UTX,
    unsigned short* __restrict__ UTH, float* __restrict__ CX,
    float* __restrict__ CH, float* __restrict__ BC)
{
  int tid = blockIdx.x * 256 + threadIdx.x;
  if (tid < 131072) {                       // VC: gate-interleave + bf16, 8 elems/thread
    int row = tid >> 5, kc = tid & 31, k = kc * 8;
    int jb = row >> 7, nt = row & 127, g = nt >> 5, j = jb * 32 + (nt & 31);
    int vrow = g * HH + j;
    const float* src = (k < 128) ? (Vx + vrow * RR + k) : (Vh + vrow * RR + (k - 128));
    f32x4 a = *(const f32x4*)src;
    f32x4 b = *(const f32x4*)(src + 4);
    u16x8 o;
    o[0]=f2bf(a[0]); o[1]=f2bf(a[1]); o[2]=f2bf(a[2]); o[3]=f2bf(a[3]);
    o[4]=f2bf(b[0]); o[5]=f2bf(b[1]); o[6]=f2bf(b[2]); o[7]=f2bf(b[3]);
    *(u16x8*)(VC + row * 256 + k) = o;
  } else if (tid < 139264) {                // UTX: transpose U_x -> [n][k] bf16
    int idx = tid - 131072;
    int n = idx & 127, k = (idx >> 7) * 8;
    u16x8 o;
    #pragma unroll
    for (int e = 0; e < 8; ++e) o[e] = f2bf(Ux[(k + e) * RR + n]);
    *(u16x8*)(UTX + n * II + k) = o;
  } else if (tid < 155648) {                // UTH: transpose U_h -> [n][k] bf16
    int idx = tid - 139264;
    int n = idx & 127, k = (idx >> 7) * 8;
    u16x8 o;
    #pragma unroll
    for (int e = 0; e < 8; ++e) o[e] = f2bf(Uh[(k + e) * RR + n]);
    *(u16x8*)(UTH + n * HH + k) = o;
  } else if (tid < 157696) {                // corr_x[g][i]
    int idx = tid - 155648;
    int g = idx >> 9, i = idx & 511;
    const float* u = Ux + i * RR;
    const float* v = Vx + (g * HH + i) * RR;
    float s = 0.f;
    #pragma unroll 8
    for (int r4 = 0; r4 < 32; ++r4) {
      f32x4 uu = *(const f32x4*)(u + r4 * 4);
      f32x4 vv = *(const f32x4*)(v + r4 * 4);
      s += uu[0]*vv[0] + uu[1]*vv[1] + uu[2]*vv[2] + uu[3]*vv[3];
    }
    CX[g * II + i] = s;
  } else if (tid < 161792) {                // corr_h[g][j]
    int idx = tid - 157696;
    int g = idx >> 10, j = idx & 1023;
    const float* u = Uh + j * RR;
    const float* v = Vh + (g * HH + j) * RR;
    float s = 0.f;
    #pragma unroll 8
    for (int r4 = 0; r4 < 32; ++r4) {
      f32x4 uu = *(const f32x4*)(u + r4 * 4);
      f32x4 vv = *(const f32x4*)(v + r4 * 4);
      s += uu[0]*vv[0] + uu[1]*vv[1] + uu[2]*vv[2] + uu[3]*vv[3];
    }
    CH[g * HH + j] = s;
  } else if (tid < 165888) {                // combined bias
    int n = tid - 161792;
    BC[n] = bx[n] + bh[n];
  }
}

// ---- stage1 v2: barrier-free K-split-across-waves thin GEMM ----
// Block = 16 output rows x 128 cols. 4 waves each own K/4 (no barriers in
// K-loop: all global loads pipeline). Cross-wave reduce via padded LDS.
template<int K, int NKS>
__device__ __forceinline__ void s1_core(
    const float* __restrict__ src, const unsigned short* __restrict__ Ut,
    unsigned short* __restrict__ T, float* __restrict__ Red,
    int b0, int p, int t)
{
  int l = t & 63, w = t >> 6;
  int row = l & 15, kof = (l >> 4) * 8;
  int kc0 = w * (K / 4);
  const float* ap = src + (b0 + row) * K + kc0 + kof;
  const unsigned short* bp = Ut + row * K + kc0 + kof;

  f32x4 acc[8];
  #pragma unroll
  for (int fi = 0; fi < 8; ++fi) acc[fi] = (f32x4){0.f, 0.f, 0.f, 0.f};

  #pragma unroll
  for (int ks = 0; ks < NKS; ++ks) {
    f32x4 a0 = *(const f32x4*)(ap + ks * 32);
    f32x4 a1 = *(const f32x4*)(ap + ks * 32 + 4);
    union { bf16x8 v; unsigned short u[8]; } af;
    af.u[0]=f2bf(a0[0]); af.u[1]=f2bf(a0[1]); af.u[2]=f2bf(a0[2]); af.u[3]=f2bf(a0[3]);
    af.u[4]=f2bf(a1[0]); af.u[5]=f2bf(a1[1]); af.u[6]=f2bf(a1[2]); af.u[7]=f2bf(a1[3]);
    #pragma unroll
    for (int fi = 0; fi < 8; ++fi) {
      bf16x8 bf = *(const bf16x8*)(bp + fi * 16 * K + ks * 32);
      acc[fi] = __builtin_amdgcn_mfma_f32_16x16x32_bf16(af.v, bf, acc[fi], 0, 0, 0);
    }
  }

  // partials -> LDS [4 waves][16 rows][132 cols] (stride 132: <=2-way conflicts)
  #pragma unroll
  for (int fi = 0; fi < 8; ++fi) {
    int n = fi * 16 + row;
    #pragma unroll
    for (int reg = 0; reg < 4; ++reg) {
      int m = (l >> 4) * 4 + reg;
      Red[(w * 16 + m) * 132 + n] = acc[fi][reg];
    }
  }
  __syncthreads();

  // reduce 4 waves, convert, store T
  #pragma unroll
  for (int it = 0; it < 2; ++it) {
    int q = it * 256 + t;
    int m = q >> 5, c4 = (q & 31) * 4;
    f32x4 s0 = *(const f32x4*)(Red + (0 * 16 + m) * 132 + c4);
    f32x4 s1 = *(const f32x4*)(Red + (1 * 16 + m) * 132 + c4);
    f32x4 s2 = *(const f32x4*)(Red + (2 * 16 + m) * 132 + c4);
    f32x4 s3 = *(const f32x4*)(Red + (3 * 16 + m) * 132 + c4);
    f32x4 s = s0 + s1 + s2 + s3;
    u16x4 o;
    o[0]=f2bf(s[0]); o[1]=f2bf(s[1]); o[2]=f2bf(s[2]); o[3]=f2bf(s[3]);
    *(u16x4*)(T + (b0 + m) * 256 + p * 128 + c4) = o;
  }
}

__global__ __launch_bounds__(256) void stage1_kernel(
    const float* __restrict__ x, const float* __restrict__ h,
    const unsigned short* __restrict__ UTX, const unsigned short* __restrict__ UTH,
    unsigned short* __restrict__ T)
{
  __shared__ alignas(16) float Red[4 * 16 * 132];   // 33792 B
  int t = threadIdx.x;
  int mb = blockIdx.x & 255;
  if (blockIdx.x < 256) s1_core<II, II / 128>(x, UTX, T, Red, mb * 16, 0, t);
  else                  s1_core<HH, HH / 128>(h, UTH, T, Red, mb * 16, 1, t);
}

// ---- stage2 v2: V tile in LDS (one barrier), A-fragments direct from
// L2-resident T. 1024 blocks x 512 thr; LDS 67.6 KB -> 2 blocks/CU.
__global__ __launch_bounds__(512) void stage2_kernel(
    const unsigned short* __restrict__ T, const unsigned short* __restrict__ VC,
    const float* __restrict__ CX, const float* __restrict__ CH, const float* __restrict__ BC,
    const float* __restrict__ x, const float* __restrict__ h, const float* __restrict__ c,
    const float* __restrict__ dx, const float* __restrict__ dh,
    float* __restrict__ out)
{
  __shared__ alignas(16) unsigned short Vs[128 * 264];  // +8 pad
  int t = threadIdx.x, l = t & 63, w = t >> 6;
  int jb = blockIdx.x >> 5, mb = blockIdx.x & 31;
  int b0 = mb * 128, j0 = jb * 32;

  #pragma unroll
  for (int i = 0; i < 8; ++i) {
    int f = i * 512 + t;
    int r = f >> 5, kc = (f & 31) * 8;
    *(u16x8*)(Vs + r * 264 + kc) = *(const u16x8*)(VC + (jb * 128 + r) * 256 + kc);
  }
  __syncthreads();

  int row = l & 15, koff = (l >> 4) * 8;
  const unsigned short* ap = T + (b0 + w * 16 + row) * 256 + koff;

  f32x4 acc[8];
  #pragma unroll
  for (int fi = 0; fi < 8; ++fi) acc[fi] = (f32x4){0.f, 0.f, 0.f, 0.f};

  #pragma unroll
  for (int ks = 0; ks < 8; ++ks) {
    bf16x8 a = *(const bf16x8*)(ap + ks * 32);
    #pragma unroll
    for (int fi = 0; fi < 8; ++fi) {
      bf16x8 b = *(const bf16x8*)(Vs + (fi * 16 + row) * 264 + ks * 32 + koff);
      acc[fi] = __builtin_amdgcn_mfma_f32_16x16x32_bf16(a, b, acc[fi], 0, 0, 0);
    }
  }

  // epilogue: fragment (fi = g*2 + hl), col = g*32 + hl*16 + (l&15)
  #pragma unroll
  for (int reg = 0; reg < 4; ++reg) {
    int b = b0 + w * 16 + (l >> 4) * 4 + reg;
    #pragma unroll
    for (int hl = 0; hl < 2; ++hl) {
      int j = j0 + hl * 16 + (l & 15);
      float hv = h[b * HH + j];
      float cv = c[b * HH + j];
      float addv = dh[j] * hv;
      float pre[4];
      #pragma unroll
      for (int g = 0; g < 4; ++g) pre[g] = acc[g * 2 + hl][reg];
      if (j0 < II) {
        float xv = x[b * II + j];
        addv += dx[j] * xv;
        #pragma unroll
        for (int g = 0; g < 4; ++g) pre[g] -= xv * CX[g * II + j];
      }
      #pragma unroll
      for (int g = 0; g < 4; ++g) pre[g] += BC[g * HH + j] + addv - hv * CH[g * HH + j];
      float ig = sigm(pre[0]);
      float fg = sigm(pre[1]);
      float og = sigm(pre[2]);
      float ng = tanh_f(pre[3]);
      float cn = fg * cv + ig * ng;
      float hn = og * tanh_f(cn);
      out[b * HH + j] = hn;
      out[BB * HH + b * HH + j] = cn;
    }
  }
}

extern "C" void kernel_launch(void* const* d_in, const int* in_sizes, int n_in,
                              void* d_out, int out_size, void* d_ws, size_t ws_size,
                              hipStream_t stream) {
  const float* x  = (const float*)d_in[0];
  const float* h  = (const float*)d_in[1];
  const float* c  = (const float*)d_in[2];
  const float* Ux = (const float*)d_in[3];
  const float* Uh = (const float*)d_in[4];
  const float* Vx = (const float*)d_in[5];
  const float* Vh = (const float*)d_in[6];
  const float* bx = (const float*)d_in[7];
  const float* bh = (const float*)d_in[8];
  const float* dx = (const float*)d_in[9];
  const float* dh = (const float*)d_in[10];
  char* ws = (char*)d_ws;
  unsigned short* T   = (unsigned short*)(ws + 0);
  unsigned short* VC  = (unsigned short*)(ws + 2097152);
  unsigned short* UTX = (unsigned short*)(ws + 4194304);
  unsigned short* UTH = (unsigned short*)(ws + 4325376);
  float* CX = (float*)(ws + 4587520);
  float* CH = (float*)(ws + 4595712);
  float* BC = (float*)(ws + 4612096);
  float* out = (float*)d_out;

  prep_kernel<<<648, 256, 0, stream>>>(Ux, Uh, Vx, Vh, bx, bh, VC, UTX, UTH, CX, CH, BC);
  stage1_kernel<<<512, 256, 0, stream>>>(x, h, UTX, UTH, T);
  stage2_kernel<<<1024, 512, 0, stream>>>(T, VC, CX, CH, BC, x, h, c, dx, dh, out);
}